// Round 16
// baseline (796.842 us; speedup 1.0000x reference)
//
#include <hip/hip_runtime.h>
#include <math.h>

// ---------------------------------------------------------------------------
// Coherent DONN: 3 x (phase mask -> ifft2(fft2(f)*H)) -> |f|^2 -> FC(10)
// R23: TRANSPOSED PING-PONG LAYOUT — kill the column-tile kernel.
//   k_col's ~117 us proved structural (R13/R17/R21/R22: every per-wave
//   cost trade was null): tile staging + barriers + segment loads exist
//   only because column data is non-contiguous. Fix the LAYOUT: every
//   row pass writes its output TRANSPOSED via an 8x512 LDS tile + 32-B
//   segment writes (R8/R20: writes do NOT amplify at 32-B granularity;
//   only reads do). Then the "column" pass (k_cmid) reads contiguous
//   rows of the transposed buffer and is k_rmid-shaped: per-wave FFT in
//   registers, streaming, no cross-wave tile, no staging barriers.
//   Layout chain: x[y][x] -r1-> B[kx][y] -cmid-> A[y][kx] -rmid->
//   B[kx][y] -cmid-> A -rmid-> B -cmid-> A[y][kx] -rlast (unchanged).
//   Ping-pong costs a 2nd field buffer: PER_IMG 1->2 MB, M~64, 2 chunks.
// Keeps: persistent+prefetch (R18/R19), soft LDS fences (same-wave DS
// in-order, HW-verified R17), separable hx/hy with 1/512+1/512 scale
// split (R22), launch-per-block k_rlast (R20).
// Field stored fp16 complex (half2v, 4 B/elem); compute fp32.
// FFT: 512-pt Stockham radix-8, 64 threads (1 wave) per FFT, 3 stages.
// ---------------------------------------------------------------------------

#define PAD(i) ((i) + ((i) >> 4))      // LDS padding: breaks 16-element strides
#define LSTR 545                        // per-wave FFT scratch (float2 elems)

typedef __attribute__((ext_vector_type(2))) _Float16 half2v;  // 4 B field elem
typedef __attribute__((ext_vector_type(8))) _Float16 half8;   // 16 B = 4 elems

// Compiler-only ordering for same-wave LDS exchange (emits no instruction;
// same-wave DS ops are processed in issue order by HW — verified R17).
__device__ __forceinline__ void wave_lds_order() {
  asm volatile("" ::: "memory");
}

__device__ __forceinline__ float2 cadd(float2 a, float2 b){ return make_float2(a.x+b.x, a.y+b.y); }
__device__ __forceinline__ float2 csub(float2 a, float2 b){ return make_float2(a.x-b.x, a.y-b.y); }
__device__ __forceinline__ float2 cmul(float2 a, float2 b){ return make_float2(a.x*b.x - a.y*b.y, a.x*b.y + a.y*b.x); }

// S=-1: a*b ; S=+1: a*conj(b)  (tw tables hold FORWARD twiddles e^{-i...})
template<int S>
__device__ __forceinline__ float2 cmul_s(float2 a, float2 b) {
  return (S < 0) ? make_float2(a.x*b.x - a.y*b.y, a.x*b.y + a.y*b.x)
                 : make_float2(a.x*b.x + a.y*b.y, a.y*b.x - a.x*b.y);
}

template<int S>  // multiply by S*i  (S=-1 forward, S=+1 inverse)
__device__ __forceinline__ float2 crot(float2 z){
  return (S > 0) ? make_float2(-z.y, z.x) : make_float2(z.y, -z.x);
}

// natural-order DFT-8: V[k] = sum_n v[n] e^{S*2pi*i*nk/8}
template<int S>
__device__ __forceinline__ void fft8(float2 v[8]) {
  const float sq = 0.70710678118654752440f;
  float2 t0 = cadd(v[0], v[4]), t1 = csub(v[0], v[4]);
  float2 t2 = cadd(v[2], v[6]), t3 = csub(v[2], v[6]);
  float2 E0 = cadd(t0, t2), E2 = csub(t0, t2);
  float2 rt3 = crot<S>(t3);
  float2 E1 = cadd(t1, rt3), E3 = csub(t1, rt3);
  float2 u0 = cadd(v[1], v[5]), u1 = csub(v[1], v[5]);
  float2 u2 = cadd(v[3], v[7]), u3 = csub(v[3], v[7]);
  float2 O0 = cadd(u0, u2), O2 = csub(u0, u2);
  float2 ru3 = crot<S>(u3);
  float2 O1 = cadd(u1, ru3), O3 = csub(u1, ru3);
  float2 O1w = make_float2(sq*(O1.x - (float)S*O1.y), sq*((float)S*O1.x + O1.y));
  float2 O2w = crot<S>(O2);
  float2 O3w = make_float2(-sq*(O3.x + (float)S*O3.y), sq*((float)S*O3.x - O3.y));
  v[0] = cadd(E0, O0);  v[4] = csub(E0, O0);
  v[1] = cadd(E1, O1w); v[5] = csub(E1, O1w);
  v[2] = cadd(E2, O2w); v[6] = csub(E2, O2w);
  v[3] = cadd(E3, O3w); v[7] = csub(E3, O3w);
}

// Forward twiddle tables: tw2[r-1]=e^{-2pi*i*r*(t&7)/64}, tw3=.../512
__device__ __forceinline__ void mktw(float2 tw2[7], float2 tw3[7], int t) {
  float a2 = -6.28318530717958647692f * (float)(t & 7) / 64.0f;
  float a3 = -6.28318530717958647692f * (float)(t & 63) / 512.0f;
  float s2, c2; __sincosf(a2, &s2, &c2);
  float s3, c3; __sincosf(a3, &s3, &c3);
  float2 w2 = make_float2(c2, s2), w3 = make_float2(c3, s3);
  tw2[0] = w2; tw3[0] = w3;
  #pragma unroll
  for (int r = 1; r < 7; ++r) { tw2[r] = cmul(tw2[r-1], w2); tw3[r] = cmul(tw3[r-1], w3); }
}

// Soft-fenced single-row 512-pt FFT with tables (per-wave scratch B).
template<int S>
__device__ __forceinline__ void fft512_w(float2 v[8], float2* __restrict__ B, int t,
                                         const float2 tw2[7], const float2 tw3[7]) {
  fft8<S>(v);
  #pragma unroll
  for (int r = 0; r < 8; ++r) B[PAD(8*t + r)] = v[r];
  wave_lds_order();
  #pragma unroll
  for (int r = 0; r < 8; ++r) v[r] = B[PAD(t + 64*r)];
  #pragma unroll
  for (int r = 1; r < 8; ++r) v[r] = cmul_s<S>(v[r], tw2[r-1]);
  fft8<S>(v);
  int d = ((t >> 3) << 6) | (t & 7);
  #pragma unroll
  for (int r = 0; r < 8; ++r) B[PAD(d + 8*r)] = v[r];
  wave_lds_order();
  #pragma unroll
  for (int r = 0; r < 8; ++r) v[r] = B[PAD(t + 64*r)];
  #pragma unroll
  for (int r = 1; r < 8; ++r) v[r] = cmul_s<S>(v[r], tw3[r-1]);
  fft8<S>(v);
}

// fp16 field element helpers
__device__ __forceinline__ float2 h2f(half2v h) { return make_float2((float)h[0], (float)h[1]); }
__device__ __forceinline__ half2v f2h(float2 v) { half2v h; h[0] = (_Float16)v.x; h[1] = (_Float16)v.y; return h; }

// Store-T tail: wave w holds v[8] (elements t+64r of its row). Stage into
// an fp16 tile [8][512] aliased onto the FFT scratch, then each thread
// writes one output "column"'s 8 elements (32 B contiguous) to
// dst[(size_t)j*512 + rowbase .. +7]. 32-B segments do not amplify
// WRITE_SIZE (R8/R20 measured). 3 barriers incl. WAR for the next iter.
__device__ __forceinline__ void store_T(float2* lds, const float2 v[8],
                                        int t, int w, int tid,
                                        half2v* __restrict__ dst, int rowbase) {
  __syncthreads();                       // all waves done with FFT scratch
  half2v* tile = (half2v*)lds;           // [8][512] fp16, 16 KB alias
  #pragma unroll
  for (int r = 0; r < 8; ++r) tile[w * 512 + t + 64*r] = f2h(v[r]);
  __syncthreads();
  int j = tid;                           // 512 threads = 512 output cols
  half2v seg[8];
  #pragma unroll
  for (int w2 = 0; w2 < 8; ++w2) seg[w2] = tile[w2 * 512 + j];
  float4* d4 = (float4*)(dst + (size_t)j * 512 + rowbase);
  d4[0] = *(float4*)&seg[0];
  d4[1] = *(float4*)&seg[4];
  __syncthreads();                       // WAR: scratch reused next iter
}

// ---------------------------------------------------------------------------

// Separable transfer function tables, fp64 phase (kz ~ 4.1e5 rad).
// hx[u] = e^{-i pi lam z fu^2};  hy[w] = e^{i(kz - pi lam z fw^2)} / 512.
// (1/N^2 split: 1/512 here, 1/512 applied in fp32 regs in k_cmid.)
__global__ __launch_bounds__(256) void k_hinit(float2* __restrict__ hx,
                                               float2* __restrict__ hy) {
  int idx = blockIdx.x * 256 + threadIdx.x;          // 0..1023
  int u = idx & 511;
  double f = (double)(u < 256 ? u : u - 512) * 1953.125;  // 1/(512*1e-6)
  const double LAM = 5.32e-7, ZD = 0.035;
  const double PI = 3.14159265358979323846;
  double s, c;
  if (idx < 512) {
    double ang = -PI * LAM * ZD * f * f;
    sincos(ang, &s, &c);
    hx[u] = make_float2((float)c, (float)s);
  } else {
    double ang = (2.0 * PI / LAM) * ZD - PI * LAM * ZD * f * f;
    sincos(ang, &s, &c);
    const double sc = 1.0 / 512.0;
    hy[u] = make_float2((float)(c * sc), (float)(s * sc));
  }
}

// P1 (persistent, 8 rows/block): field = x * e^{i*phi0}; row FFT over x;
// store-T: Bout[kx][y].
__global__ __launch_bounds__(512) void k_r1(const float* __restrict__ x,
                                            const float* __restrict__ ph,
                                            half2v* __restrict__ Bout, int ng) {
  __shared__ float2 lds[8 * LSTR];       // 34.9 KB (FFT scratch + tile alias)
  int tid = threadIdx.x;
  int t = tid & 63, w = tid >> 6;
  float2 tw2[7], tw3[7];
  mktw(tw2, tw3, t);
  int grp = blockIdx.x;
  float pfx[8], pfp[8];
  if (grp < ng) {                        // prologue prefetch
    size_t row = (size_t)grp * 8 + w;
    const float* xr = x + row * 512;
    const float* pr = ph + (size_t)(row & 511) * 512;
    #pragma unroll
    for (int r = 0; r < 8; ++r) { pfx[r] = xr[t + 64*r]; pfp[r] = pr[t + 64*r]; }
  }
  while (grp < ng) {
    float2 v[8];
    #pragma unroll
    for (int r = 0; r < 8; ++r) {        // consume prefetch regs
      float sn, cs; __sincosf(pfp[r], &sn, &cs);
      v[r] = make_float2(pfx[r] * cs, pfx[r] * sn);
    }
    int next = grp + (int)gridDim.x;     // issue next group's loads now
    if (next < ng) {
      size_t nrow = (size_t)next * 8 + w;
      const float* xr = x + nrow * 512;
      const float* pr = ph + (size_t)(nrow & 511) * 512;
      #pragma unroll
      for (int r = 0; r < 8; ++r) { pfx[r] = xr[t + 64*r]; pfp[r] = pr[t + 64*r]; }
    }
    fft512_w<-1>(v, lds + w * LSTR, t, tw2, tw3);
    int bimg = (grp * 8) >> 9, rowbase = (grp * 8) & 511;
    store_T(lds, v, t, w, tid, Bout + (size_t)bimg * 262144, rowbase);
    grp = next;
  }
}

// P2/P4/P6 (persistent, 8 kx-rows/block): reads Bin[kx][y] rows
// (contiguous); FFT over y -> ky; * hy(ky)*hx(kx); iFFT over ky -> y;
// *1/512 (reg); store-T: Aout[y][kx]. Streaming, no tile staging.
__global__ __launch_bounds__(512) void k_cmid(const half2v* __restrict__ Bin,
                                              half2v* __restrict__ Aout,
                                              const float2* __restrict__ hx,
                                              const float2* __restrict__ hy,
                                              int ng) {
  __shared__ float2 lds[8 * LSTR];
  int tid = threadIdx.x;
  int t = tid & 63, w = tid >> 6;
  float2 hyv[8];
  #pragma unroll
  for (int r = 0; r < 8; ++r) hyv[r] = hy[t + 64*r];
  float2 tw2[7], tw3[7];
  mktw(tw2, tw3, t);
  int grp = blockIdx.x;
  half2v pff[8];
  if (grp < ng) {                        // prologue prefetch
    int bimg = (grp * 8) >> 9, kx = (grp * 8 + w) & 511;
    const half2v* src = Bin + (size_t)bimg * 262144 + (size_t)kx * 512;
    #pragma unroll
    for (int r = 0; r < 8; ++r) pff[r] = src[t + 64*r];
  }
  while (grp < ng) {
    int bimg = (grp * 8) >> 9, kx = (grp * 8 + w) & 511;
    float2 v[8];
    #pragma unroll
    for (int r = 0; r < 8; ++r) v[r] = h2f(pff[r]);
    int next = grp + (int)gridDim.x;     // issue next group's loads now
    if (next < ng) {
      int nb = (next * 8) >> 9, nkx = (next * 8 + w) & 511;
      const half2v* src = Bin + (size_t)nb * 262144 + (size_t)nkx * 512;
      #pragma unroll
      for (int r = 0; r < 8; ++r) pff[r] = src[t + 64*r];
    }
    fft512_w<-1>(v, lds + w * LSTR, t, tw2, tw3);   // FFT over y -> ky
    float2 hxv = hx[kx];
    #pragma unroll
    for (int r = 0; r < 8; ++r) v[r] = cmul(cmul(v[r], hyv[r]), hxv);
    fft512_w<1>(v, lds + w * LSTR, t, tw2, tw3);    // iFFT over ky -> y
    const float s512 = 1.0f / 512.0f;    // second half of the 1/N^2 split
    #pragma unroll
    for (int r = 0; r < 8; ++r) { v[r].x *= s512; v[r].y *= s512; }
    int rowbase = (grp * 8) & 511;       // kx base of this group
    store_T(lds, v, t, w, tid, Aout + (size_t)bimg * 262144, rowbase);
    grp = next;
  }
}

// P3/P5 (persistent, 8 y-rows/block): reads Ain[y][kx] rows; iFFT over kx
// -> x; * e^{i*phi}; FFT over x -> kx; store-T: Bout[kx][y].
__global__ __launch_bounds__(512) void k_rmid(const half2v* __restrict__ Ain,
                                              half2v* __restrict__ Bout,
                                              const float* __restrict__ ph, int ng) {
  __shared__ float2 lds[8 * LSTR];
  int tid = threadIdx.x;
  int t = tid & 63, w = tid >> 6;
  float2 tw2[7], tw3[7];
  mktw(tw2, tw3, t);
  int grp = blockIdx.x;
  half2v pff[8]; float pfp[8];
  if (grp < ng) {                        // prologue prefetch
    int bimg = (grp * 8) >> 9, y = (grp * 8 + w) & 511;
    const half2v* src = Ain + (size_t)bimg * 262144 + (size_t)y * 512;
    const float* pr = ph + (size_t)y * 512;
    #pragma unroll
    for (int r = 0; r < 8; ++r) { pff[r] = src[t + 64*r]; pfp[r] = pr[t + 64*r]; }
  }
  while (grp < ng) {
    int bimg = (grp * 8) >> 9;
    float2 v[8]; float cur_p[8];
    #pragma unroll
    for (int r = 0; r < 8; ++r) { v[r] = h2f(pff[r]); cur_p[r] = pfp[r]; }
    int next = grp + (int)gridDim.x;     // issue next group's loads now
    if (next < ng) {
      int nb = (next * 8) >> 9, nyy = (next * 8 + w) & 511;
      const half2v* src = Ain + (size_t)nb * 262144 + (size_t)nyy * 512;
      const float* pr = ph + (size_t)nyy * 512;
      #pragma unroll
      for (int r = 0; r < 8; ++r) { pff[r] = src[t + 64*r]; pfp[r] = pr[t + 64*r]; }
    }
    fft512_w<1>(v, lds + w * LSTR, t, tw2, tw3);    // iFFT over kx -> x
    #pragma unroll
    for (int r = 0; r < 8; ++r) {
      float sn, cs; __sincosf(cur_p[r], &sn, &cs);
      v[r] = cmul(v[r], make_float2(cs, sn));
    }
    fft512_w<-1>(v, lds + w * LSTR, t, tw2, tw3);   // FFT over x -> kx
    int rowbase = (grp * 8) & 511;       // y base of this group
    store_T(lds, v, t, w, tid, Bout + (size_t)bimg * 262144, rowbase);
    grp = next;
  }
}

// P7 (launch-per-block, unchanged R20 form): reads A[y][kx] rows; iFFT over
// kx -> intensity -> dot with 10 class rows -> partial[g][c][y].
// Same-y blocks adjacent -> W hot in L2.
__global__ __launch_bounds__(256) void k_rlast(const half2v* __restrict__ F,
                                               const float* __restrict__ W,
                                               float* __restrict__ partial, int m) {
  __shared__ float2 lds[4 * LSTR];
  int tid = threadIdx.x;
  int t = tid & 63, rl = tid >> 6;
  int nq = (m + 3) >> 2;
  int y = blockIdx.x / nq;               // same-y blocks adjacent -> W hot in L2
  int q = blockIdx.x - y * nq;
  int g = q * 4 + rl;                    // image within chunk
  bool act = (g < m);
  const half2v* Fr = F + ((size_t)g * 262144 + (size_t)y * 512);
  float2 tw2[7], tw3[7];
  mktw(tw2, tw3, t);
  float2 v[8];
  #pragma unroll
  for (int r = 0; r < 8; ++r) {
    half2v h = act ? Fr[t + 64*r] : (half2v)(_Float16)0.0f;
    v[r] = h2f(h);
  }
  fft512_w<1>(v, lds + rl * LSTR, t, tw2, tw3);
  float acc[10];
  #pragma unroll
  for (int c = 0; c < 10; ++c) acc[c] = 0.0f;
  const float* Wy = W + (size_t)y * 512;
  #pragma unroll
  for (int r = 0; r < 8; ++r) {
    int e = t + 64*r;
    float I = v[r].x * v[r].x + v[r].y * v[r].y;
    #pragma unroll
    for (int c = 0; c < 10; ++c) acc[c] += I * Wy[(size_t)c * 262144 + e];
  }
  float mine = 0.0f;
  #pragma unroll
  for (int c = 0; c < 10; ++c) {
    float s = acc[c];
    #pragma unroll
    for (int off = 32; off > 0; off >>= 1) s += __shfl_xor(s, off, 64);
    if (t == c) mine = s;
  }
  if (act && t < 10)
    partial[((size_t)g * 10 + t) * 512 + y] = mine;
}

// FC tail: out[g][c] = fc_b[c] + sum_y partial[g][c][y].  One wave per (g,c).
__global__ __launch_bounds__(64) void k_fc(const float* __restrict__ partial,
                                           const float* __restrict__ fc_b,
                                           float* __restrict__ out, int b0, int m) {
  int bid = blockIdx.x;                  // m*10
  int g = bid / 10, c = bid - g * 10;
  int t = threadIdx.x;
  const float* p = partial + ((size_t)g * 10 + c) * 512;
  float s = 0.0f;
  #pragma unroll
  for (int r = 0; r < 8; ++r) s += p[t + 64*r];
  #pragma unroll
  for (int off = 32; off > 0; off >>= 1) s += __shfl_xor(s, off, 64);
  if (t == 0) out[(size_t)(b0 + g) * 10 + c] = s + fc_b[c];
}

// ---------------------------------------------------------------------------

extern "C" void kernel_launch(void* const* d_in, const int* in_sizes, int n_in,
                              void* d_out, int out_size, void* d_ws, size_t ws_size,
                              hipStream_t stream) {
  const float* x    = (const float*)d_in[0];   // (128,1,512,512)
  const float* ph   = (const float*)d_in[1];   // (3,512,512)
  const float* fc_w = (const float*)d_in[2];   // (10, 262144)
  const float* fc_b = (const float*)d_in[3];   // (10,)
  float* out = (float*)d_out;                  // (128,10)

  const size_t IMG = 262144;                   // 512*512
  // Ping-pong field buffers A,B (fp16 each) + per-image partials.
  const size_t PER_IMG = 2 * IMG * sizeof(half2v) + 512 * 10 * sizeof(float);
  float2* hx = (float2*)d_ws;                  // 512 float2
  float2* hy = hx + 512;                       // 512 float2
  size_t hdr = 1024 * sizeof(float2);
  size_t avail = (ws_size > hdr) ? ws_size - hdr : 0;
  int M = (int)(avail / PER_IMG);              // images per chunk
  if (M < 1) M = 1;
  if (M > 128) M = 128;
  half2v* A = (half2v*)((char*)d_ws + hdr);
  half2v* B = A + (size_t)M * IMG;
  float* part = (float*)(B + (size_t)M * IMG);

  hipLaunchKernelGGL(k_hinit, dim3(4), dim3(256), 0, stream, hx, hy);

  for (int b0 = 0; b0 < 128; b0 += M) {
    int m = (128 - b0 < M) ? (128 - b0) : M;
    int ng = m * 64;                           // 8-row groups
    int g512 = ng < 1024 ? ng : 1024;          // persistent grids
    int nq = (m + 3) >> 2;
    hipLaunchKernelGGL(k_r1,   dim3(g512), dim3(512), 0, stream,
                       x + (size_t)b0 * IMG, ph, B, ng);
    hipLaunchKernelGGL(k_cmid, dim3(g512), dim3(512), 0, stream,
                       (const half2v*)B, A, (const float2*)hx, (const float2*)hy, ng);
    hipLaunchKernelGGL(k_rmid, dim3(g512), dim3(512), 0, stream,
                       (const half2v*)A, B, ph + IMG, ng);
    hipLaunchKernelGGL(k_cmid, dim3(g512), dim3(512), 0, stream,
                       (const half2v*)B, A, (const float2*)hx, (const float2*)hy, ng);
    hipLaunchKernelGGL(k_rmid, dim3(g512), dim3(512), 0, stream,
                       (const half2v*)A, B, ph + 2 * IMG, ng);
    hipLaunchKernelGGL(k_cmid, dim3(g512), dim3(512), 0, stream,
                       (const half2v*)B, A, (const float2*)hx, (const float2*)hy, ng);
    hipLaunchKernelGGL(k_rlast, dim3(512 * nq), dim3(256), 0, stream,
                       (const half2v*)A, fc_w, part, m);
    hipLaunchKernelGGL(k_fc,   dim3(m * 10), dim3(64), 0, stream, part, fc_b, out, b0, m);
  }
}